// Round 1
// baseline (180.526 us; speedup 1.0000x reference)
//
#include <hip/hip_runtime.h>

// Problem constants (match reference)
#define NQ 50000
#define NS 50000
#define MNB 32
#define KP 15
#define DF 64
#define KFLAT (KP * DF)   // 960

typedef __bf16 bf16x8 __attribute__((ext_vector_type(8)));
typedef float  f32x4  __attribute__((ext_vector_type(4)));

__device__ __forceinline__ unsigned short f2bf(float f) {
    union { float f; unsigned int u; } v; v.f = f;
    unsigned int u = v.u;
    unsigned int r = (u + 0x7FFFu + ((u >> 16) & 1u)) >> 16;  // RNE
    return (unsigned short)r;
}

// ---------------------------------------------------------------------------
// Stage 1: per-query wave kernel.
// weighted[n][k][d] = sum_m max(0, 1 - |p_nb - p_q - kp_k|) * x[nb][d]
// One wave (64 lanes) per query; 4 queries per 256-thread block.
// Output: ws row (bf16) of 960 = 15*64 values, layout k*64+d (matches the
// reference reshape of weight[K][D_IN][D_OUT] -> [960][64]).
// ---------------------------------------------------------------------------
__global__ __launch_bounds__(256) void kpconv_stage1(
    const float* __restrict__ qp, const float* __restrict__ sp,
    const int* __restrict__ nb, const float* __restrict__ x,
    const float* __restrict__ kpts, unsigned short* __restrict__ ws,
    int base, int cn)
{
    __shared__ float kp_s[48];          // 15*3 kernel-point coords
    __shared__ float w_s[4][KP][MNB];   // influence weights, [k][m]: m = bank, conflict-free
    __shared__ int   nb_s[4][MNB];

    const int tid = threadIdx.x;
    if (tid < KP * 3) kp_s[tid] = kpts[tid];
    __syncthreads();

    const int wv   = tid >> 6;
    const int lane = tid & 63;
    const int row_l = blockIdx.x * 4 + wv;
    const int n = base + row_l;
    const bool active = (row_l < cn);

    if (active) {
        // ---- phase A: influence weights. lanes 0-31 do k=0..7, 32-63 do k=8..14
        const int m  = lane & 31;
        const int kh = lane >> 5;
        int idx = nb[n * MNB + m];
        if (kh == 0) nb_s[wv][m] = idx;
        const float qx = qp[n * 3 + 0], qy = qp[n * 3 + 1], qz = qp[n * 3 + 2];
        float sx, sy, sz;
        if (idx < NS) { sx = sp[idx * 3 + 0]; sy = sp[idx * 3 + 1]; sz = sp[idx * 3 + 2]; }
        else          { sx = 1e6f; sy = 1e6f; sz = 1e6f; }   // shadow point
        const float rx = sx - qx, ry = sy - qy, rz = sz - qz;
        #pragma unroll
        for (int kk = 0; kk < 8; ++kk) {
            const int k = kh * 8 + kk;
            if (k < KP) {
                const float dx = rx - kp_s[k * 3 + 0];
                const float dy = ry - kp_s[k * 3 + 1];
                const float dz = rz - kp_s[k * 3 + 2];
                const float d2 = dx * dx + dy * dy + dz * dz;
                w_s[wv][k][m] = fmaxf(1.0f - sqrtf(d2), 0.0f);
            }
        }
    }
    __syncthreads();
    if (!active) return;

    // ---- phase B: lane = feature channel d. Gather 32 neighbor rows (256B
    // coalesced each), then 15x32 FMAs against LDS-broadcast float4 weights.
    float f[MNB];
    #pragma unroll
    for (int m = 0; m < MNB; ++m) {
        int idx = nb_s[wv][m];
        idx = (idx < NS) ? idx : 0;     // shadow: w==0, value irrelevant
        f[m] = x[(size_t)idx * DF + lane];
    }
    unsigned short* wrow = ws + (size_t)row_l * KFLAT;
    #pragma unroll
    for (int k = 0; k < KP; ++k) {
        float a = 0.0f;
        const float4* wr = (const float4*)(&w_s[wv][k][0]);
        #pragma unroll
        for (int m4 = 0; m4 < 8; ++m4) {
            const float4 w4 = wr[m4];
            a = fmaf(w4.x, f[m4 * 4 + 0], a);
            a = fmaf(w4.y, f[m4 * 4 + 1], a);
            a = fmaf(w4.z, f[m4 * 4 + 2], a);
            a = fmaf(w4.w, f[m4 * 4 + 3], a);
        }
        wrow[k * DF + lane] = f2bf(a);
    }
}

// ---------------------------------------------------------------------------
// Stage 2: out[N,64] = weighted[N,960] @ W[960,64] via bf16 MFMA 16x16x32.
// Block = 256 threads (4 waves) covers a 64-row x 64-col tile.
// weight is converted to bf16 in LDS in B-fragment order, in two 480-k halves
// (60 KB each) to stay under the 64 KB per-block LDS cap.
// Fragment layouts (m89/m120-verified):
//   A: lane holds A[r=lane&15][k=8*(lane>>4)+j], j=0..7  (16B contiguous)
//   B: lane holds B[k=8*(lane>>4)+j][c=lane&15]
//   D: lane holds D[r=4*(lane>>4)+i][c=lane&15], i=0..3
// ---------------------------------------------------------------------------
__global__ __launch_bounds__(256) void kpconv_stage2(
    const unsigned short* __restrict__ wsA, const float* __restrict__ W,
    float* __restrict__ out, int base, int cn)
{
    __shared__ __align__(16) unsigned short w_s[480 * 64];   // 61440 B

    const int tid  = threadIdx.x;
    const int lane = tid & 63;
    const int wv   = tid >> 6;
    const int cl   = lane & 15;
    const int q    = lane >> 4;
    const int n0   = blockIdx.x * 64;

    f32x4 acc[4];
    #pragma unroll
    for (int cb = 0; cb < 4; ++cb) acc[cb] = (f32x4){0.f, 0.f, 0.f, 0.f};

    for (int half = 0; half < 2; ++half) {
        // ---- fill LDS with bf16 weight half, B-fragment swizzled:
        // lds 16B chunk [kg*64 + c] holds W[half*480 + kg*8 + j][c], j=0..7
        {
            const int c  = tid & 63;
            const int tg = tid >> 6;
            for (int kg = tg; kg < 60; kg += 4) {
                const int gk = half * 480 + kg * 8;
                union { unsigned short s[8]; uint4 u; } pk;
                #pragma unroll
                for (int j = 0; j < 8; ++j)
                    pk.s[j] = f2bf(W[(size_t)(gk + j) * 64 + c]);   // 256B coalesced loads
                ((uint4*)w_s)[kg * 64 + c] = pk.u;                   // conflict-free b128 write
            }
        }
        __syncthreads();

        const unsigned short* arow =
            wsA + (size_t)(n0 + wv * 16 + cl) * KFLAT + half * 480 + q * 8;
        #pragma unroll
        for (int ks = 0; ks < 15; ++ks) {
            union { uint4 u; bf16x8 v; } au;
            au.u = *(const uint4*)(arow + ks * 32);     // global_load_dwordx4
            const bf16x8 a = au.v;
            #pragma unroll
            for (int cb = 0; cb < 4; ++cb) {
                const bf16x8 b = *(const bf16x8*)&w_s[(4 * ks + q) * 512 + (cb * 16 + cl) * 8];
                acc[cb] = __builtin_amdgcn_mfma_f32_16x16x32_bf16(a, b, acc[cb], 0, 0, 0);
            }
        }
        __syncthreads();
    }

    // ---- epilogue: D layout row = q*4+i, col = cb*16+cl
    #pragma unroll
    for (int cb = 0; cb < 4; ++cb) {
        #pragma unroll
        for (int i = 0; i < 4; ++i) {
            const int r = n0 + wv * 16 + q * 4 + i;
            if (r < cn)
                out[(size_t)(base + r) * 64 + cb * 16 + cl] = acc[cb][i];
        }
    }
}

// ---------------------------------------------------------------------------
extern "C" void kernel_launch(void* const* d_in, const int* in_sizes, int n_in,
                              void* d_out, int out_size, void* d_ws, size_t ws_size,
                              hipStream_t stream) {
    const float* qp   = (const float*)d_in[0];
    const float* sp   = (const float*)d_in[1];
    const int*   nb   = (const int*)d_in[2];
    const float* x    = (const float*)d_in[3];
    const float* kpts = (const float*)d_in[4];
    const float* W    = (const float*)d_in[5];
    float* out = (float*)d_out;
    unsigned short* ws = (unsigned short*)d_ws;

    // Chunk queries so the bf16 weighted buffer (rows*1920 B) fits in ws.
    long long cap = (long long)(ws_size / (KFLAT * 2));
    int rows_cap = (cap > 50048) ? 50048 : (int)cap;
    rows_cap -= rows_cap & 63;          // multiple of 64
    if (rows_cap < 64) rows_cap = 64;   // assume ws >= 120 KB

    for (int base = 0; base < NQ; base += rows_cap) {
        const int cn = (NQ - base < rows_cap) ? (NQ - base) : rows_cap;
        hipLaunchKernelGGL(kpconv_stage1, dim3((cn + 3) / 4), dim3(256), 0, stream,
                           qp, sp, nb, x, kpts, ws, base, cn);
        hipLaunchKernelGGL(kpconv_stage2, dim3((cn + 63) / 64), dim3(256), 0, stream,
                           ws, W, out, base, cn);
    }
}

// Round 2
// 179.499 us; speedup vs baseline: 1.0057x; 1.0057x over previous
//
#include <hip/hip_runtime.h>

#define NQ 50000
#define NS 50000
#define MNB 32
#define KP 15
#define DF 64
#define KFLAT (KP * DF)   // 960

typedef __bf16 bf16x8 __attribute__((ext_vector_type(8)));
typedef float  f32x4  __attribute__((ext_vector_type(4)));
typedef float  f32x2  __attribute__((ext_vector_type(2)));

__device__ __forceinline__ unsigned short f2bf(float f) {
    union { float f; unsigned int u; } v; v.f = f;
    unsigned int u = v.u;
    return (unsigned short)((u + 0x7FFFu + ((u >> 16) & 1u)) >> 16);  // RNE
}
__device__ __forceinline__ float bflo2f(unsigned int u) {   // low bf16 -> f32
    union { unsigned int u; float f; } v; v.u = u << 16; return v.f;
}
__device__ __forceinline__ float bfhi2f(unsigned int u) {   // high bf16 -> f32
    union { unsigned int u; float f; } v; v.u = u & 0xFFFF0000u; return v.f;
}

// ---------------------------------------------------------------------------
// Preconvert x [NS,64] f32 -> bf16 (packed pairs). n4 = NS*DF/2 uints.
// ---------------------------------------------------------------------------
__global__ __launch_bounds__(256) void conv_x(const float* __restrict__ x,
                                              unsigned int* __restrict__ xb, int n4) {
    const int i = blockIdx.x * 256 + threadIdx.x;   // 4 uints = 8 floats each
    if (i * 4 + 3 < n4) {
        const float4* s = (const float4*)x + i * 2;
        const float4 a0 = s[0], a1 = s[1];
        uint4 o;
        o.x = (unsigned)f2bf(a0.x) | ((unsigned)f2bf(a0.y) << 16);
        o.y = (unsigned)f2bf(a0.z) | ((unsigned)f2bf(a0.w) << 16);
        o.z = (unsigned)f2bf(a1.x) | ((unsigned)f2bf(a1.y) << 16);
        o.w = (unsigned)f2bf(a1.z) | ((unsigned)f2bf(a1.w) << 16);
        ((uint4*)xb)[i] = o;
    }
}

// ---------------------------------------------------------------------------
// Preconvert weight [960][64] f32 -> bf16 in B-fragment-swizzled order:
// 16B chunk (half, kg, c) holds W[half*480 + kg*8 + j][c], j=0..7.
// chunk index = (half*60 + kg)*64 + c ; 7680 chunks total.
// ---------------------------------------------------------------------------
__global__ __launch_bounds__(256) void conv_w(const float* __restrict__ W,
                                              uint4* __restrict__ wBf) {
    const int chunk = blockIdx.x * 256 + threadIdx.x;
    if (chunk >= 7680) return;
    const int half = chunk / 3840;
    const int rem  = chunk - half * 3840;
    const int kg   = rem >> 6, c = rem & 63;
    union { unsigned short s[8]; uint4 u; } pk;
    #pragma unroll
    for (int j = 0; j < 8; ++j)
        pk.s[j] = f2bf(W[(size_t)(half * 480 + kg * 8 + j) * 64 + c]);
    wBf[chunk] = pk.u;
}

// ---------------------------------------------------------------------------
// Stage 1: 2 queries per wave (half-wave each), 2 channels per lane (float2).
// weighted[n][k][d] = sum_m max(0, 1-|p_nb - p_q - kp_k|) * x[nb][d], bf16 out.
// ---------------------------------------------------------------------------
__global__ __launch_bounds__(256) void kpconv_stage1(
    const float* __restrict__ qp, const float* __restrict__ sp,
    const int* __restrict__ nb, const unsigned int* __restrict__ xb,
    const float* __restrict__ kpts, unsigned int* __restrict__ wsW,
    int base, int cn)
{
    __shared__ float kp_s[45];
    __shared__ float w_s[8][KP][MNB];   // [query-slot][k][m]: m=bank, conflict-free
    __shared__ int   nb_s[8][MNB];

    const int tid = threadIdx.x;
    if (tid < 45) kp_s[tid] = kpts[tid];
    __syncthreads();

    const int wv = tid >> 6, lane = tid & 63;
    const int h = lane >> 5, m = lane & 31;
    const int qs = wv * 2 + h;                    // query slot in block (0..7)
    const int row_l = blockIdx.x * 8 + qs;
    const bool active = (row_l < cn);
    const int n = active ? (base + row_l) : 0;

    // ---- phase A: lane m computes all 15 influence weights for its neighbor
    int idx = active ? nb[n * MNB + m] : 0;
    nb_s[qs][m] = idx;
    const float qx = qp[n * 3 + 0], qy = qp[n * 3 + 1], qz = qp[n * 3 + 2];
    float sx = 1e6f, sy = 1e6f, sz = 1e6f;
    if (idx < NS) { sx = sp[idx * 3 + 0]; sy = sp[idx * 3 + 1]; sz = sp[idx * 3 + 2]; }
    const float rx = sx - qx, ry = sy - qy, rz = sz - qz;
    #pragma unroll
    for (int k = 0; k < KP; ++k) {
        const float dx = rx - kp_s[k * 3 + 0];
        const float dy = ry - kp_s[k * 3 + 1];
        const float dz = rz - kp_s[k * 3 + 2];
        const float d2 = dx * dx + dy * dy + dz * dz;
        w_s[qs][k][m] = fmaxf(1.0f - sqrtf(d2), 0.0f);
    }
    __syncthreads();
    if (!active) return;

    // ---- phase B: lane = channel pair c (d=2c,2c+1). 32 coalesced 128B gathers.
    const int c = m;
    f32x2 f[MNB];
    #pragma unroll
    for (int mm = 0; mm < MNB; ++mm) {
        int id2 = nb_s[qs][mm];
        if (id2 >= NS) id2 = 0;                  // shadow: w==0, value irrelevant
        const unsigned u = xb[(size_t)id2 * 32 + c];
        f[mm] = (f32x2){ bflo2f(u), bfhi2f(u) };
    }
    unsigned int* wrow = wsW + (size_t)row_l * (KFLAT / 2);
    #pragma unroll
    for (int k = 0; k < KP; ++k) {
        f32x2 a = (f32x2){0.f, 0.f};
        const float4* wr = (const float4*)&w_s[qs][k][0];   // uniform per half-wave
        #pragma unroll
        for (int m4 = 0; m4 < 8; ++m4) {
            const float4 w4 = wr[m4];
            a += f[m4 * 4 + 0] * w4.x;
            a += f[m4 * 4 + 1] * w4.y;
            a += f[m4 * 4 + 2] * w4.z;
            a += f[m4 * 4 + 3] * w4.w;
        }
        wrow[k * 32 + c] = (unsigned)f2bf(a.x) | ((unsigned)f2bf(a.y) << 16);
    }
}

// ---------------------------------------------------------------------------
// Stage 2: out[N,64] = weighted[N,960] @ W[960,64], bf16 MFMA 16x16x32.
// 64-row x 64-col tile per 256-thread block; pre-swizzled bf16 weight halves
// staged via 15 uint4 copies/thread (no conversion work).
// ---------------------------------------------------------------------------
__global__ __launch_bounds__(256) void kpconv_stage2(
    const unsigned short* __restrict__ wsW, const uint4* __restrict__ wBf,
    float* __restrict__ out, int base, int cn)
{
    __shared__ __align__(16) unsigned short w_s[3840 * 8];   // 61440 B

    const int tid  = threadIdx.x;
    const int lane = tid & 63;
    const int wv   = tid >> 6;
    const int cl   = lane & 15;
    const int q    = lane >> 4;
    const int n0   = blockIdx.x * 64;

    f32x4 acc[4];
    #pragma unroll
    for (int cb = 0; cb < 4; ++cb) acc[cb] = (f32x4){0.f, 0.f, 0.f, 0.f};

    for (int half = 0; half < 2; ++half) {
        const uint4* src = wBf + half * 3840;
        for (int i = tid; i < 3840; i += 256)
            ((uint4*)w_s)[i] = src[i];           // coalesced 16B copies
        __syncthreads();

        const unsigned short* arow =
            wsW + (size_t)(n0 + wv * 16 + cl) * KFLAT + half * 480 + q * 8;
        #pragma unroll
        for (int ks = 0; ks < 15; ++ks) {
            union { uint4 u; bf16x8 v; } au;
            au.u = *(const uint4*)(arow + ks * 32);
            #pragma unroll
            for (int cb = 0; cb < 4; ++cb) {
                const bf16x8 b = *(const bf16x8*)&w_s[((ks * 4 + q) * 64 + cb * 16 + cl) * 8];
                acc[cb] = __builtin_amdgcn_mfma_f32_16x16x32_bf16(au.v, b, acc[cb], 0, 0, 0);
            }
        }
        __syncthreads();
    }

    #pragma unroll
    for (int cb = 0; cb < 4; ++cb) {
        #pragma unroll
        for (int i = 0; i < 4; ++i) {
            const int r = n0 + wv * 16 + q * 4 + i;
            if (r < cn)
                out[(size_t)(base + r) * 64 + cb * 16 + cl] = acc[cb][i];
        }
    }
}

// ---------------------------------------------------------------------------
extern "C" void kernel_launch(void* const* d_in, const int* in_sizes, int n_in,
                              void* d_out, int out_size, void* d_ws, size_t ws_size,
                              hipStream_t stream) {
    const float* qp   = (const float*)d_in[0];
    const float* sp   = (const float*)d_in[1];
    const int*   nb   = (const int*)d_in[2];
    const float* x    = (const float*)d_in[3];
    const float* kpts = (const float*)d_in[4];
    const float* W    = (const float*)d_in[5];
    float* out = (float*)d_out;

    // ws layout (ushort elements): [0..61440) swizzled bf16 weight,
    // [61440..61440+3.2M) bf16 x, rest: bf16 weighted rows (1920 B each).
    unsigned short* wsu = (unsigned short*)d_ws;
    uint4*          wBf = (uint4*)d_ws;                         // 122880 B
    unsigned int*   xb  = (unsigned int*)(wsu + 61440);         // 6.4 MB
    unsigned short* wsW = wsu + 61440 + 3200000;

    long long cap = ((long long)ws_size - 6522880LL) / (KFLAT * 2);
    int rows_cap = (cap > 50048) ? 50048 : (int)cap;
    rows_cap &= ~63;
    if (rows_cap < 64) rows_cap = 64;   // ws is known >= 96 MB from round 1

    hipLaunchKernelGGL(conv_x, dim3(1563), dim3(256), 0, stream, x, xb, NS * DF / 2);
    hipLaunchKernelGGL(conv_w, dim3(30), dim3(256), 0, stream, W, wBf);

    for (int base = 0; base < NQ; base += rows_cap) {
        const int cn = (NQ - base < rows_cap) ? (NQ - base) : rows_cap;
        hipLaunchKernelGGL(kpconv_stage1, dim3((cn + 7) / 8), dim3(256), 0, stream,
                           qp, sp, nb, xb, kpts, (unsigned int*)wsW, base, cn);
        hipLaunchKernelGGL(kpconv_stage2, dim3((cn + 63) / 64), dim3(256), 0, stream,
                           wsW, wBf, out, base, cn);
    }
}

// Round 3
// 160.741 us; speedup vs baseline: 1.1231x; 1.1167x over previous
//
#include <hip/hip_runtime.h>

#define NQ 50000
#define NS 50000
#define MNB 32
#define KP 15
#define DF 64
#define KFLAT (KP * DF)   // 960

typedef __bf16 bf16x8 __attribute__((ext_vector_type(8)));
typedef float  f32x4  __attribute__((ext_vector_type(4)));
typedef float  f32x2  __attribute__((ext_vector_type(2)));

__device__ __forceinline__ unsigned short f2bf(float f) {
    union { float f; unsigned int u; } v; v.f = f;
    unsigned int u = v.u;
    return (unsigned short)((u + 0x7FFFu + ((u >> 16) & 1u)) >> 16);  // RNE
}
__device__ __forceinline__ float bflo2f(unsigned int u) {
    union { unsigned int u; float f; } v; v.u = u << 16; return v.f;
}
__device__ __forceinline__ float bfhi2f(unsigned int u) {
    union { unsigned int u; float f; } v; v.u = u & 0xFFFF0000u; return v.f;
}

// ---------------------------------------------------------------------------
// Preconvert x [NS,64] f32 -> bf16 packed pairs.
// ---------------------------------------------------------------------------
__global__ __launch_bounds__(256) void conv_x(const float* __restrict__ x,
                                              unsigned int* __restrict__ xb, int n4) {
    const int i = blockIdx.x * 256 + threadIdx.x;
    if (i * 4 + 3 < n4) {
        const float4* s = (const float4*)x + i * 2;
        const float4 a0 = s[0], a1 = s[1];
        uint4 o;
        o.x = (unsigned)f2bf(a0.x) | ((unsigned)f2bf(a0.y) << 16);
        o.y = (unsigned)f2bf(a0.z) | ((unsigned)f2bf(a0.w) << 16);
        o.z = (unsigned)f2bf(a1.x) | ((unsigned)f2bf(a1.y) << 16);
        o.w = (unsigned)f2bf(a1.z) | ((unsigned)f2bf(a1.w) << 16);
        ((uint4*)xb)[i] = o;
    }
}

// ---------------------------------------------------------------------------
// Preconvert weight [960][64] f32 -> bf16, B-fragment-swizzled (see stage2).
// ---------------------------------------------------------------------------
__global__ __launch_bounds__(256) void conv_w(const float* __restrict__ W,
                                              uint4* __restrict__ wBf) {
    const int chunk = blockIdx.x * 256 + threadIdx.x;
    if (chunk >= 7680) return;
    const int half = chunk / 3840;
    const int rem  = chunk - half * 3840;
    const int kg   = rem >> 6, c = rem & 63;
    union { unsigned short s[8]; uint4 u; } pk;
    #pragma unroll
    for (int j = 0; j < 8; ++j)
        pk.s[j] = f2bf(W[(size_t)(half * 480 + kg * 8 + j) * 64 + c]);
    wBf[chunk] = pk.u;
}

// ---------------------------------------------------------------------------
// Stage 1 (sparse): per query, compact the list of neighbors with any
// nonzero influence (random neighbors => ~35% active), then accumulate only
// those. 2 queries/wave (half-wave each), lane = channel-pair in phase B.
// ---------------------------------------------------------------------------
__global__ __launch_bounds__(256, 6) void kpconv_stage1(
    const float* __restrict__ qp, const float* __restrict__ sp,
    const int* __restrict__ nb, const unsigned int* __restrict__ xb,
    const float* __restrict__ kpts, unsigned int* __restrict__ wsW,
    int base, int cn)
{
    __shared__ float kp_s[45];
    __shared__ __align__(16) float w_s[8][MNB][20];  // padded 80B rows, 20.5 KB
    __shared__ unsigned int am_s[8][MNB];            // packed (id<<5)|m, compacted
    __shared__ int acnt_s[8];

    const int tid = threadIdx.x;
    if (tid < 45) kp_s[tid] = kpts[tid];
    __syncthreads();

    const int lane = tid & 63, wv = tid >> 6;
    const int h = lane >> 5, m = lane & 31;
    const int qs = wv * 2 + h;                 // query slot 0..7
    const int row_l = blockIdx.x * 8 + qs;
    const bool active = (row_l < cn);
    const int n = active ? (base + row_l) : 0;

    // ---- phase A: lane m computes 15 influence weights for neighbor m
    const int id = nb[n * MNB + m];
    const float qx = qp[n * 3 + 0], qy = qp[n * 3 + 1], qz = qp[n * 3 + 2];
    float sx = 1e6f, sy = 1e6f, sz = 1e6f;
    if (id < NS) { sx = sp[id * 3 + 0]; sy = sp[id * 3 + 1]; sz = sp[id * 3 + 2]; }
    const float rx = sx - qx, ry = sy - qy, rz = sz - qz;
    float wk[KP];
    float wmax = 0.0f;
    #pragma unroll
    for (int k = 0; k < KP; ++k) {
        const float dx = rx - kp_s[k * 3 + 0];
        const float dy = ry - kp_s[k * 3 + 1];
        const float dz = rz - kp_s[k * 3 + 2];
        const float d2 = dx * dx + dy * dy + dz * dz;
        wk[k] = fmaxf(1.0f - sqrtf(d2), 0.0f);
        wmax = fmaxf(wmax, wk[k]);
    }
    const bool any = active && (wmax > 0.0f);
    if (any) {
        float4* wr = (float4*)&w_s[qs][m][0];
        wr[0] = make_float4(wk[0], wk[1], wk[2], wk[3]);
        wr[1] = make_float4(wk[4], wk[5], wk[6], wk[7]);
        wr[2] = make_float4(wk[8], wk[9], wk[10], wk[11]);
        wr[3] = make_float4(wk[12], wk[13], wk[14], 0.0f);
    }
    const unsigned long long bal = __ballot(any);
    const unsigned int hm = (unsigned int)(bal >> (h * 32));
    if (any) {
        const int pos = __popc(hm & ((1u << m) - 1u));
        am_s[qs][pos] = ((unsigned)id << 5) | (unsigned)m;
    }
    if (m == 0) acnt_s[qs] = __popc(hm);
    __syncthreads();
    if (!active) return;

    // ---- phase B: lane = channel pair c; loop only over active neighbors
    const int c = m;
    const int A = acnt_s[qs];
    f32x2 acc[KP];
    #pragma unroll
    for (int k = 0; k < KP; ++k) acc[k] = (f32x2){0.f, 0.f};

    for (int j = 0; j < A; ++j) {
        const unsigned e = am_s[qs][j];          // uniform per half-wave
        const int mm = (int)(e & 31u);
        const unsigned idj = e >> 5;
        const unsigned u = xb[(size_t)idj * 32 + c];   // 128B coalesced gather
        const f32x2 f = (f32x2){ bflo2f(u), bfhi2f(u) };
        const float4* wr = (const float4*)&w_s[qs][mm][0];  // broadcast reads
        const float4 w0 = wr[0], w1 = wr[1], w2 = wr[2], w3 = wr[3];
        acc[0]  += f * w0.x;  acc[1]  += f * w0.y;  acc[2]  += f * w0.z;  acc[3]  += f * w0.w;
        acc[4]  += f * w1.x;  acc[5]  += f * w1.y;  acc[6]  += f * w1.z;  acc[7]  += f * w1.w;
        acc[8]  += f * w2.x;  acc[9]  += f * w2.y;  acc[10] += f * w2.z;  acc[11] += f * w2.w;
        acc[12] += f * w3.x;  acc[13] += f * w3.y;  acc[14] += f * w3.z;
    }

    unsigned int* wrow = wsW + (size_t)row_l * (KFLAT / 2);
    #pragma unroll
    for (int k = 0; k < KP; ++k)
        wrow[k * 32 + c] = (unsigned)f2bf(acc[k].x) | ((unsigned)f2bf(acc[k].y) << 16);
}

// ---------------------------------------------------------------------------
// Stage 2: out[N,64] = weighted[N,960] @ W[960,64], bf16 MFMA 16x16x32.
// ---------------------------------------------------------------------------
__global__ __launch_bounds__(256) void kpconv_stage2(
    const unsigned short* __restrict__ wsW, const uint4* __restrict__ wBf,
    float* __restrict__ out, int base, int cn)
{
    __shared__ __align__(16) unsigned short w_s[3840 * 8];   // 61440 B

    const int tid  = threadIdx.x;
    const int lane = tid & 63;
    const int wv   = tid >> 6;
    const int cl   = lane & 15;
    const int q    = lane >> 4;
    const int n0   = blockIdx.x * 64;

    f32x4 acc[4];
    #pragma unroll
    for (int cb = 0; cb < 4; ++cb) acc[cb] = (f32x4){0.f, 0.f, 0.f, 0.f};

    for (int half = 0; half < 2; ++half) {
        const uint4* src = wBf + half * 3840;
        for (int i = tid; i < 3840; i += 256)
            ((uint4*)w_s)[i] = src[i];
        __syncthreads();

        const unsigned short* arow =
            wsW + (size_t)(n0 + wv * 16 + cl) * KFLAT + half * 480 + q * 8;
        #pragma unroll
        for (int ks = 0; ks < 15; ++ks) {
            union { uint4 u; bf16x8 v; } au;
            au.u = *(const uint4*)(arow + ks * 32);
            #pragma unroll
            for (int cb = 0; cb < 4; ++cb) {
                const bf16x8 b = *(const bf16x8*)&w_s[((ks * 4 + q) * 64 + cb * 16 + cl) * 8];
                acc[cb] = __builtin_amdgcn_mfma_f32_16x16x32_bf16(au.v, b, acc[cb], 0, 0, 0);
            }
        }
        __syncthreads();
    }

    #pragma unroll
    for (int cb = 0; cb < 4; ++cb) {
        #pragma unroll
        for (int i = 0; i < 4; ++i) {
            const int r = n0 + wv * 16 + q * 4 + i;
            if (r < cn)
                out[(size_t)(base + r) * 64 + cb * 16 + cl] = acc[cb][i];
        }
    }
}

// ---------------------------------------------------------------------------
extern "C" void kernel_launch(void* const* d_in, const int* in_sizes, int n_in,
                              void* d_out, int out_size, void* d_ws, size_t ws_size,
                              hipStream_t stream) {
    const float* qp   = (const float*)d_in[0];
    const float* sp   = (const float*)d_in[1];
    const int*   nb   = (const int*)d_in[2];
    const float* x    = (const float*)d_in[3];
    const float* kpts = (const float*)d_in[4];
    const float* W    = (const float*)d_in[5];
    float* out = (float*)d_out;

    unsigned short* wsu = (unsigned short*)d_ws;
    uint4*          wBf = (uint4*)d_ws;                         // 122880 B
    unsigned int*   xb  = (unsigned int*)(wsu + 61440);         // 6.4 MB
    unsigned short* wsW = wsu + 61440 + 3200000;

    long long cap = ((long long)ws_size - 6522880LL) / (KFLAT * 2);
    int rows_cap = (cap > 50048) ? 50048 : (int)cap;
    rows_cap &= ~63;
    if (rows_cap < 64) rows_cap = 64;

    hipLaunchKernelGGL(conv_x, dim3(1563), dim3(256), 0, stream, x, xb, NS * DF / 2);
    hipLaunchKernelGGL(conv_w, dim3(30), dim3(256), 0, stream, W, wBf);

    for (int base = 0; base < NQ; base += rows_cap) {
        const int cn = (NQ - base < rows_cap) ? (NQ - base) : rows_cap;
        hipLaunchKernelGGL(kpconv_stage1, dim3((cn + 7) / 8), dim3(256), 0, stream,
                           qp, sp, nb, xb, kpts, (unsigned int*)wsW, base, cn);
        hipLaunchKernelGGL(kpconv_stage2, dim3((cn + 63) / 64), dim3(256), 0, stream,
                           wsW, wBf, out, base, cn);
    }
}

// Round 4
// 156.182 us; speedup vs baseline: 1.1559x; 1.0292x over previous
//
#include <hip/hip_runtime.h>

#define NQ 50000
#define NS 50000
#define MNB 32
#define KP 15
#define DF 64
#define KFLAT (KP * DF)     // 960
#define WTS 968             // wt LDS row stride (ushorts): 960 + 8 pad (bank spread)

typedef __bf16 bf16x8 __attribute__((ext_vector_type(8)));
typedef float  f32x4  __attribute__((ext_vector_type(4)));
typedef float  f32x2  __attribute__((ext_vector_type(2)));

__device__ __forceinline__ unsigned short f2bf(float f) {
    union { float f; unsigned int u; } v; v.f = f;
    unsigned int u = v.u;
    return (unsigned short)((u + 0x7FFFu + ((u >> 16) & 1u)) >> 16);  // RNE
}
__device__ __forceinline__ float bflo2f(unsigned int u) {
    union { unsigned int u; float f; } v; v.u = u << 16; return v.f;
}
__device__ __forceinline__ float bfhi2f(unsigned int u) {
    union { unsigned int u; float f; } v; v.u = u & 0xFFFF0000u; return v.f;
}

// ---------------------------------------------------------------------------
// Preconvert x [NS,64] f32 -> bf16 packed pairs.
// ---------------------------------------------------------------------------
__global__ __launch_bounds__(256) void conv_x(const float* __restrict__ x,
                                              unsigned int* __restrict__ xb, int n4) {
    const int i = blockIdx.x * 256 + threadIdx.x;
    if (i * 4 + 3 < n4) {
        const float4* s = (const float4*)x + i * 2;
        const float4 a0 = s[0], a1 = s[1];
        uint4 o;
        o.x = (unsigned)f2bf(a0.x) | ((unsigned)f2bf(a0.y) << 16);
        o.y = (unsigned)f2bf(a0.z) | ((unsigned)f2bf(a0.w) << 16);
        o.z = (unsigned)f2bf(a1.x) | ((unsigned)f2bf(a1.y) << 16);
        o.w = (unsigned)f2bf(a1.z) | ((unsigned)f2bf(a1.w) << 16);
        ((uint4*)xb)[i] = o;
    }
}

// ---------------------------------------------------------------------------
// Preconvert weight [960][64] f32 -> bf16, B-fragment-swizzled:
// uint4 chunk t*64+c (t=0..119, c=0..63) holds W[t*8+j][c], j=0..7.
// MFMA step ks (k=32ks..32ks+31), lane q-group q: fragment = chunk (4ks+q)*64+c.
// ---------------------------------------------------------------------------
__global__ __launch_bounds__(256) void conv_w(const float* __restrict__ W,
                                              uint4* __restrict__ wBf) {
    const int chunk = blockIdx.x * 256 + threadIdx.x;
    if (chunk >= 7680) return;
    const int t = chunk >> 6, c = chunk & 63;
    union { unsigned short s[8]; uint4 u; } pk;
    #pragma unroll
    for (int j = 0; j < 8; ++j)
        pk.s[j] = f2bf(W[(size_t)(t * 8 + j) * 64 + c]);
    wBf[chunk] = pk.u;
}

// ---------------------------------------------------------------------------
// Fused KPConv: 16 queries per 256-thread block (grid = 3125, exact).
// Phase 1 (x2 sweeps): sparse influence + feature aggregation (r3 scheme),
//   weighted rows -> bf16 LDS tile wt[16][WTS].
// Phase 2: out[16,64] = wt[16,960] @ W[960,64]; wave wv does col-block wv,
//   30 MFMAs, B-fragments streamed from L2-resident pre-swizzled wBf.
// ---------------------------------------------------------------------------
__global__ __launch_bounds__(256, 4) void kpconv_fused(
    const float* __restrict__ qp, const float* __restrict__ sp,
    const int* __restrict__ nb, const unsigned int* __restrict__ xb,
    const float* __restrict__ kpts, const uint4* __restrict__ wBf,
    float* __restrict__ out)
{
    __shared__ float kp_s[45];
    __shared__ __align__(16) float w_s[8][MNB][16];     // influence, 16 KB
    __shared__ unsigned int am_s[8][MNB];               // compacted (id<<5)|m
    __shared__ int acnt_s[8];
    __shared__ __align__(16) unsigned short wt_s[16 * WTS];  // 30976 B

    const int tid = threadIdx.x;
    if (tid < 45) kp_s[tid] = kpts[tid];
    __syncthreads();

    const int lane = tid & 63, wv = tid >> 6;
    const int h = lane >> 5, m = lane & 31;
    const int slot = wv * 2 + h;                 // 0..7 per sweep
    const int n0 = blockIdx.x * 16;

    for (int s = 0; s < 2; ++s) {
        const int qs = s * 8 + slot;             // query slot 0..15
        const int n = n0 + qs;                   // grid exact: n < NQ always

        // ---- phase A: lane m -> 15 influence weights for neighbor m
        const int id = nb[n * MNB + m];
        const float qx = qp[n * 3 + 0], qy = qp[n * 3 + 1], qz = qp[n * 3 + 2];
        float sx = 1e6f, sy = 1e6f, sz = 1e6f;
        if (id < NS) { sx = sp[id * 3 + 0]; sy = sp[id * 3 + 1]; sz = sp[id * 3 + 2]; }
        const float rx = sx - qx, ry = sy - qy, rz = sz - qz;
        float wk[KP], wmax = 0.0f;
        #pragma unroll
        for (int k = 0; k < KP; ++k) {
            const float dx = rx - kp_s[k * 3 + 0];
            const float dy = ry - kp_s[k * 3 + 1];
            const float dz = rz - kp_s[k * 3 + 2];
            const float d2 = dx * dx + dy * dy + dz * dz;
            wk[k] = fmaxf(1.0f - sqrtf(d2), 0.0f);
            wmax = fmaxf(wmax, wk[k]);
        }
        const bool any = (wmax > 0.0f);
        if (any) {
            float4* wr = (float4*)&w_s[slot][m][0];
            wr[0] = make_float4(wk[0], wk[1], wk[2], wk[3]);
            wr[1] = make_float4(wk[4], wk[5], wk[6], wk[7]);
            wr[2] = make_float4(wk[8], wk[9], wk[10], wk[11]);
            wr[3] = make_float4(wk[12], wk[13], wk[14], 0.0f);
        }
        const unsigned long long bal = __ballot(any);
        const unsigned int hm = (unsigned int)(bal >> (h * 32));
        if (any) {
            const int pos = __popc(hm & ((1u << m) - 1u));
            am_s[slot][pos] = ((unsigned)id << 5) | (unsigned)m;
        }
        if (m == 0) acnt_s[slot] = __popc(hm);
        __syncthreads();

        // ---- phase B: lane = channel pair c; only active neighbors
        const int c = m;
        const int A = acnt_s[slot];
        f32x2 acc[KP];
        #pragma unroll
        for (int k = 0; k < KP; ++k) acc[k] = (f32x2){0.f, 0.f};

        for (int j = 0; j < A; ++j) {
            const unsigned e = am_s[slot][j];               // uniform / half-wave
            const int mm = (int)(e & 31u);
            const unsigned idj = e >> 5;
            const unsigned u = xb[(size_t)idj * 32 + c];    // 128B coalesced gather
            const f32x2 f = (f32x2){ bflo2f(u), bfhi2f(u) };
            const float4* wr = (const float4*)&w_s[slot][mm][0];  // LDS broadcast
            const float4 w0 = wr[0], w1 = wr[1], w2 = wr[2], w3 = wr[3];
            acc[0]  += f * w0.x;  acc[1]  += f * w0.y;  acc[2]  += f * w0.z;  acc[3]  += f * w0.w;
            acc[4]  += f * w1.x;  acc[5]  += f * w1.y;  acc[6]  += f * w1.z;  acc[7]  += f * w1.w;
            acc[8]  += f * w2.x;  acc[9]  += f * w2.y;  acc[10] += f * w2.z;  acc[11] += f * w2.w;
            acc[12] += f * w3.x;  acc[13] += f * w3.y;  acc[14] += f * w3.z;
        }

        // bf16 row into wt tile: uint index qs*(WTS/2) + k*32 + c
        unsigned int* wrow = (unsigned int*)wt_s + qs * (WTS / 2);
        #pragma unroll
        for (int k = 0; k < KP; ++k)
            wrow[k * 32 + c] = (unsigned)f2bf(acc[k].x) | ((unsigned)f2bf(acc[k].y) << 16);
        __syncthreads();
    }

    // ---- phase 2: MFMA. wave wv -> out cols [wv*16, wv*16+16)
    const int cl = lane & 15, q = lane >> 4;
    f32x4 acc = (f32x4){0.f, 0.f, 0.f, 0.f};
    #pragma unroll 6
    for (int ks = 0; ks < 30; ++ks) {
        // A: lane holds wt[r=cl][32ks + 8q + j], j=0..7 (16B contiguous)
        const bf16x8 a = *(const bf16x8*)&wt_s[cl * WTS + ks * 32 + q * 8];
        // B: W[32ks+8q+j][wv*16+cl] = pre-swizzled chunk (4ks+q)*64 + wv*16+cl
        union { uint4 u; bf16x8 v; } bu;
        bu.u = wBf[(4 * ks + q) * 64 + wv * 16 + cl];
        acc = __builtin_amdgcn_mfma_f32_16x16x32_bf16(a, bu.v, acc, 0, 0, 0);
    }
    // D: row = q*4+i (query slot), col = wv*16+cl
    #pragma unroll
    for (int i = 0; i < 4; ++i)
        out[(size_t)(n0 + q * 4 + i) * 64 + wv * 16 + cl] = acc[i];
}

// ---------------------------------------------------------------------------
extern "C" void kernel_launch(void* const* d_in, const int* in_sizes, int n_in,
                              void* d_out, int out_size, void* d_ws, size_t ws_size,
                              hipStream_t stream) {
    const float* qp   = (const float*)d_in[0];
    const float* sp   = (const float*)d_in[1];
    const int*   nb   = (const int*)d_in[2];
    const float* x    = (const float*)d_in[3];
    const float* kpts = (const float*)d_in[4];
    const float* W    = (const float*)d_in[5];
    float* out = (float*)d_out;

    // ws: [0, 122880) swizzled bf16 weight; then bf16 x (6.4 MB)
    uint4*        wBf = (uint4*)d_ws;
    unsigned int* xb  = (unsigned int*)((char*)d_ws + 122880);

    hipLaunchKernelGGL(conv_x, dim3(1563), dim3(256), 0, stream, x, xb, NS * DF / 2);
    hipLaunchKernelGGL(conv_w, dim3(30), dim3(256), 0, stream, W, wBf);
    hipLaunchKernelGGL(kpconv_fused, dim3(NQ / 16), dim3(256), 0, stream,
                       qp, sp, nb, xb, kpts, wBf, out);
}

// Round 5
// 144.006 us; speedup vs baseline: 1.2536x; 1.0845x over previous
//
#include <hip/hip_runtime.h>

#define NQ 50000
#define NS 50000
#define MNB 32
#define KP 15
#define DF 64
#define WTS 968             // wt LDS row stride in ushorts (960 + 8 pad)

typedef __bf16 bf16x8 __attribute__((ext_vector_type(8)));
typedef float  f32x4  __attribute__((ext_vector_type(4)));
typedef float  f32x2  __attribute__((ext_vector_type(2)));

__device__ __forceinline__ unsigned short f2bf(float f) {
    union { float f; unsigned int u; } v; v.f = f;
    unsigned int u = v.u;
    return (unsigned short)((u + 0x7FFFu + ((u >> 16) & 1u)) >> 16);  // RNE
}

// ---------------------------------------------------------------------------
// Preconvert weight [960][64] f32 -> bf16, B-fragment-swizzled:
// uint4 chunk t*64+c (t=0..119, c=0..63) holds W[t*8+j][c], j=0..7.
// MFMA step ks, quad q: B-fragment = chunk (4ks+q)*64 + col.
// ---------------------------------------------------------------------------
__global__ __launch_bounds__(256) void conv_w(const float* __restrict__ W,
                                              uint4* __restrict__ wBf) {
    const int chunk = blockIdx.x * 256 + threadIdx.x;
    if (chunk >= 7680) return;
    const int t = chunk >> 6, c = chunk & 63;
    union { unsigned short s[8]; uint4 u; } pk;
    #pragma unroll
    for (int j = 0; j < 8; ++j)
        pk.s[j] = f2bf(W[(size_t)(t * 8 + j) * 64 + c]);
    wBf[chunk] = pk.u;
}

// ---------------------------------------------------------------------------
// Fused KPConv, 8 queries per 256-thread block (grid = 6250, exact).
// Phase A: sparse influence weights + active-neighbor compaction (1 query per
//          half-wave). Phase B: 4-deep pipelined feature gather + aggregation,
//          bf16 rows -> LDS tile wt[8][WTS].
// Phase 2: one 16x16x32 MFMA chain (30 steps); A rows 8..15 read trailing LDS
//          garbage -> pollutes only D rows 8..15, which are never stored.
// ---------------------------------------------------------------------------
__global__ __launch_bounds__(256, 4) void kpconv_fused(
    const float* __restrict__ qp, const float* __restrict__ sp,
    const int* __restrict__ nb, const float* __restrict__ x,
    const float* __restrict__ kpts, const uint4* __restrict__ wBf,
    float* __restrict__ out)
{
    __shared__ struct {
        __align__(16) unsigned short wt[8 * WTS];   // MUST be first: phase-2
        __align__(16) float w[8][MNB][16];          //  reads rows 8..15 into
        unsigned int am[8][MNB];                    //  these fields (garbage OK)
        int acnt[8];
        float kp[45];
    } sm;

    const int tid = threadIdx.x;
    if (tid < 45) sm.kp[tid] = kpts[tid];
    __syncthreads();

    const int lane = tid & 63, wv = tid >> 6;
    const int h = lane >> 5, m = lane & 31;
    const int slot = wv * 2 + h;                 // query slot 0..7
    const int n0 = blockIdx.x * 8;
    const int n = n0 + slot;                     // grid exact: n < NQ always

    // ---- phase A: lane m -> 15 influence weights for neighbor m
    const int id = nb[n * MNB + m];
    const float qx = qp[n * 3 + 0], qy = qp[n * 3 + 1], qz = qp[n * 3 + 2];
    float sx = 1e6f, sy = 1e6f, sz = 1e6f;
    if (id < NS) { sx = sp[id * 3 + 0]; sy = sp[id * 3 + 1]; sz = sp[id * 3 + 2]; }
    const float rx = sx - qx, ry = sy - qy, rz = sz - qz;
    float wk[KP], wmax = 0.0f;
    #pragma unroll
    for (int k = 0; k < KP; ++k) {
        const float dx = rx - sm.kp[k * 3 + 0];
        const float dy = ry - sm.kp[k * 3 + 1];
        const float dz = rz - sm.kp[k * 3 + 2];
        const float d2 = dx * dx + dy * dy + dz * dz;
        wk[k] = fmaxf(1.0f - sqrtf(d2), 0.0f);
        wmax = fmaxf(wmax, wk[k]);
    }
    const bool any = (wmax > 0.0f);
    if (any) {
        float4* wr = (float4*)&sm.w[slot][m][0];
        wr[0] = make_float4(wk[0], wk[1], wk[2], wk[3]);
        wr[1] = make_float4(wk[4], wk[5], wk[6], wk[7]);
        wr[2] = make_float4(wk[8], wk[9], wk[10], wk[11]);
        wr[3] = make_float4(wk[12], wk[13], wk[14], 0.0f);
    }
    const unsigned long long bal = __ballot(any);
    const unsigned int hm = (unsigned int)(bal >> (h * 32));
    if (any) {
        const int pos = __popc(hm & ((1u << m) - 1u));
        sm.am[slot][pos] = ((unsigned)id << 5) | (unsigned)m;
    }
    if (m == 0) sm.acnt[slot] = __popc(hm);
    __syncthreads();

    // ---- phase B: lane = channel pair c; 4-deep pipelined sparse aggregation
    const int c = m;
    const float2* __restrict__ x2 = (const float2*)x;
    f32x2 acc[KP];
    #pragma unroll
    for (int k = 0; k < KP; ++k) acc[k] = (f32x2){0.f, 0.f};

    const int A = sm.acnt[slot];

#define ACCUM(E, F)                                                         \
    {                                                                       \
        const float4* wr = (const float4*)&sm.w[slot][(E) & 31u][0];        \
        const float4 w0 = wr[0], w1 = wr[1], w2 = wr[2], w3 = wr[3];        \
        acc[0]  += (F) * w0.x;  acc[1]  += (F) * w0.y;                      \
        acc[2]  += (F) * w0.z;  acc[3]  += (F) * w0.w;                      \
        acc[4]  += (F) * w1.x;  acc[5]  += (F) * w1.y;                      \
        acc[6]  += (F) * w1.z;  acc[7]  += (F) * w1.w;                      \
        acc[8]  += (F) * w2.x;  acc[9]  += (F) * w2.y;                      \
        acc[10] += (F) * w2.z;  acc[11] += (F) * w2.w;                      \
        acc[12] += (F) * w3.x;  acc[13] += (F) * w3.y;  acc[14] += (F) * w3.z; \
    }

    int j = 0;
    for (; j + 4 <= A; j += 4) {
        const unsigned e0 = sm.am[slot][j + 0];
        const unsigned e1 = sm.am[slot][j + 1];
        const unsigned e2 = sm.am[slot][j + 2];
        const unsigned e3 = sm.am[slot][j + 3];
        const float2 t0 = x2[(size_t)(e0 >> 5) * 32 + c];   // 4 gathers in flight
        const float2 t1 = x2[(size_t)(e1 >> 5) * 32 + c];
        const float2 t2 = x2[(size_t)(e2 >> 5) * 32 + c];
        const float2 t3 = x2[(size_t)(e3 >> 5) * 32 + c];
        const f32x2 f0 = (f32x2){t0.x, t0.y}, f1 = (f32x2){t1.x, t1.y};
        const f32x2 f2 = (f32x2){t2.x, t2.y}, f3 = (f32x2){t3.x, t3.y};
        ACCUM(e0, f0) ACCUM(e1, f1) ACCUM(e2, f2) ACCUM(e3, f3)
    }
    for (; j < A; ++j) {
        const unsigned e = sm.am[slot][j];
        const float2 t = x2[(size_t)(e >> 5) * 32 + c];
        const f32x2 f = (f32x2){t.x, t.y};
        ACCUM(e, f)
    }
#undef ACCUM

    // bf16 row into wt tile
    unsigned int* wrow = (unsigned int*)sm.wt + slot * (WTS / 2);
    #pragma unroll
    for (int k = 0; k < KP; ++k)
        wrow[k * 32 + c] = (unsigned)f2bf(acc[k].x) | ((unsigned)f2bf(acc[k].y) << 16);
    __syncthreads();

    // ---- phase 2: MFMA. wave wv -> out cols [wv*16, wv*16+16)
    const int cl = lane & 15, q = lane >> 4;
    f32x4 dacc = (f32x4){0.f, 0.f, 0.f, 0.f};
    #pragma unroll 6
    for (int ks = 0; ks < 30; ++ks) {
        // A: lane holds wt[r=cl][32ks + 8q + j], j=0..7 (rows >=8: garbage)
        const bf16x8 a = *(const bf16x8*)&sm.wt[cl * WTS + ks * 32 + q * 8];
        // B: pre-swizzled chunk (4ks+q)*64 + (wv*16+cl), 256B coalesced
        union { uint4 u; bf16x8 v; } bu;
        bu.u = wBf[(4 * ks + q) * 64 + wv * 16 + cl];
        dacc = __builtin_amdgcn_mfma_f32_16x16x32_bf16(a, bu.v, dacc, 0, 0, 0);
    }
    // D: row = q*4+i; only rows 0..7 are real queries
    if (q < 2) {
        #pragma unroll
        for (int i = 0; i < 4; ++i)
            out[(size_t)(n0 + q * 4 + i) * 64 + wv * 16 + cl] = dacc[i];
    }
}

// ---------------------------------------------------------------------------
extern "C" void kernel_launch(void* const* d_in, const int* in_sizes, int n_in,
                              void* d_out, int out_size, void* d_ws, size_t ws_size,
                              hipStream_t stream) {
    const float* qp   = (const float*)d_in[0];
    const float* sp   = (const float*)d_in[1];
    const int*   nb   = (const int*)d_in[2];
    const float* x    = (const float*)d_in[3];
    const float* kpts = (const float*)d_in[4];
    const float* W    = (const float*)d_in[5];
    float* out = (float*)d_out;

    uint4* wBf = (uint4*)d_ws;   // 122880 B pre-swizzled bf16 weight

    hipLaunchKernelGGL(conv_w, dim3(30), dim3(256), 0, stream, W, wBf);
    hipLaunchKernelGGL(kpconv_fused, dim3(NQ / 8), dim3(256), 0, stream,
                       qp, sp, nb, x, kpts, wBf, out);
}